// Round 6
// baseline (725.815 us; speedup 1.0000x reference)
//
#include <hip/hip_runtime.h>

// Problem constants
constexpr int Nn = 4096, Fc = 128;
constexpr int Rr = 32, Hh = 4, Dd = 32;
constexpr int BT = 96;                          // B*T
constexpr float SCALE = 0.17677669529663687f;   // 1/sqrt(32)

// Workspace layout (float offsets)
constexpr size_t OFF_V1  = 0;                               // [BT][H][R][D] f32
constexpr size_t OFF_Z   = (size_t)BT * Hh * Rr * Dd;       // [BT][H][R]   f32
constexpr size_t OFF_BQK = OFF_Z + (size_t)BT * Hh * Rr;    // [H*R]        f32
constexpr size_t OFF_U   = OFF_BQK + 128;                   // param bf16 region

// U (ushort) offsets: WK hi (fused key·Wq), Wv hi, Wv lo
constexpr int U_WKHI = 0, U_WVHI = 16384, U_WVLO = 32768;

using short8  = __attribute__((ext_vector_type(8))) short;
using floatx4 = __attribute__((ext_vector_type(4))) float;

__device__ inline ushort f2bf(float f) {
    union { float f; unsigned u; } c{f};
    unsigned r = c.u + 0x7fffu + ((c.u >> 16) & 1u);  // RNE
    return (ushort)(r >> 16);
}
__device__ inline float bf2f(ushort u) {
    union { unsigned u; float f; } c{(unsigned)u << 16};
    return c.f;
}

// ---------------------------------------------------------------------------
// kprep: WK[h*32+r][f] = sum_d Wq[h*32+d][f]*key[r][h][d]  (bf16 hi)
//        Wv hi/lo split; bqk[h*32+r] = sum_d bq[h*32+d]*key[r][h][d] (f32)
// ---------------------------------------------------------------------------
__global__ void kprep(const float* __restrict__ Wq, const float* __restrict__ bq,
                      const float* __restrict__ Wv, const float* __restrict__ key,
                      ushort* __restrict__ U, float* __restrict__ bqk)
{
    const int idx = blockIdx.x * 256 + threadIdx.x;
    if (idx < 16384) {
        const int hr = idx >> 7, f = idx & 127;
        const int h = hr >> 5, r = hr & 31;
        float s = 0.f;
#pragma unroll
        for (int d = 0; d < 32; d++)
            s += Wq[(h * 32 + d) * 128 + f] * key[(r * 4 + h) * 32 + d];
        U[U_WKHI + idx] = f2bf(s);
    } else if (idx < 32768) {
        const int o = idx - 16384;
        const float v = Wv[o];
        const ushort h = f2bf(v);
        U[U_WVHI + o] = h;
        U[U_WVLO + o] = f2bf(v - bf2f(h));
    } else if (idx < 32768 + 128) {
        const int hr = idx - 32768;
        const int h = hr >> 5, r = hr & 31;
        float s = 0.f;
#pragma unroll
        for (int d = 0; d < 32; d++)
            s += bq[h * 32 + d] * key[(r * 4 + h) * 32 + d];
        bqk[hr] = s;
    }
}

// ---------------------------------------------------------------------------
// ka (pass A), 512 threads = 8 waves: wave (h = w&3, half = w>>2) owns 32
// rows of head h. Per-wave register demand halves vs the 256-thread version
// (acca/accv 2x2, ah[2]) -> fits the 128-VGPR cap that 16 waves/CU requires.
// LDS 75776 (xh double-buffered + 8x wave-local eT/xvT) -> 2 blocks/CU =
// 4 waves/SIMD (2x round 5). v1 outer product is wave-local over the wave's
// 32-n half (K=32), both halves atomicAdd partials (v1 is L2-resident).
// ---------------------------------------------------------------------------
__global__ __launch_bounds__(512, 4)
void ka(const float* __restrict__ x, const float* __restrict__ bv,
        const ushort* __restrict__ U, const float* __restrict__ bqk,
        float* __restrict__ v1, float* __restrict__ Z)
{
    // xh x2 [64][136] bf16 (2*17408) | 8x per-wave: eT [32][40], xvT [32][40]
    __shared__ __align__(16) char lds[75776];

    const int t = threadIdx.x;
    const int w = t >> 6, lane = t & 63;
    const int h = w & 3, half = w >> 2;
    const int quad = lane >> 4, l15 = lane & 15;
    const int bt = blockIdx.y;
    constexpr int NT = 4;

    char* wsc = lds + 34816 + w * 5120;
    ushort* eT  = (ushort*)wsc;           // [32 r][40 n-loc] bf16 (80 B rows)
    ushort* xvT = (ushort*)(wsc + 2560);  // [32 d][40 n-loc] bf16 (xv*srw)

    const ushort* WKh = U + U_WKHI;
    const ushort* Wvh = U + U_WVHI;

    float bvv[2], bqkv[2];
#pragma unroll
    for (int i = 0; i < 2; i++) {
        bvv[i]  = bv[32 * h + 16 * i + l15];
        bqkv[i] = bqk[32 * h + 16 * i + l15];
    }

    floatx4 accV1[2][2];
#pragma unroll
    for (int i = 0; i < 2; i++)
#pragma unroll
        for (int j = 0; j < 2; j++) accV1[i][j] = (floatx4)0.f;
    float zacc[2] = {0.f, 0.f};

    const float* xbase = x + ((size_t)bt * Nn + blockIdx.x * (NT * 64)) * Fc;

    // prologue: tile 0 -> regs (512 threads: 4 float4 each for 64x128 f32)
    float4 xr[4];
#pragma unroll
    for (int i = 0; i < 4; i++) xr[i] = ((const float4*)xbase)[i * 512 + t];

#pragma unroll 1
    for (int it = 0; it < NT; ++it) {
        ushort* xh = (ushort*)(lds + (it & 1) * 17408);
        // regs -> LDS (waits on the prefetch issued last iteration)
#pragma unroll
        for (int i = 0; i < 4; i++) {
            const int idx = i * 512 + t;
            const int row = idx >> 5, c4 = idx & 31;
            float4 v = xr[i];
            ushort4 hv;
            hv.x = f2bf(v.x); hv.y = f2bf(v.y); hv.z = f2bf(v.z); hv.w = f2bf(v.w);
            *(ushort4*)&xh[row * 136 + c4 * 4] = hv;
        }
        __syncthreads();   // single barrier per iteration (double-buffered xh)

        floatx4 acca[2][2], accv[2][2];
#pragma unroll
        for (int mt = 0; mt < 2; mt++)
#pragma unroll
            for (int nt = 0; nt < 2; nt++) {
                acca[mt][nt] = (floatx4)0.f;
                accv[mt][nt] = (floatx4)0.f;
            }

#pragma unroll
        for (int kc = 0; kc < 4; kc++) {
            short8 ah[2];
#pragma unroll
            for (int mt = 0; mt < 2; mt++)
                ah[mt] = *(const short8*)&xh[(32 * half + 16 * mt + l15) * 136 + kc * 32 + quad * 8];
            short8 kb2[2], vb[2];
#pragma unroll
            for (int nt = 0; nt < 2; nt++) {
                const int off = (32 * h + 16 * nt + l15) * 128 + kc * 32 + quad * 8;
                kb2[nt] = *(const short8*)&WKh[off];
                vb[nt]  = *(const short8*)&Wvh[off];
            }
#pragma unroll
            for (int mt = 0; mt < 2; mt++)
#pragma unroll
                for (int nt = 0; nt < 2; nt++) {
                    acca[mt][nt] = __builtin_amdgcn_mfma_f32_16x16x32_bf16(ah[mt], kb2[nt], acca[mt][nt], 0, 0, 0);
                    accv[mt][nt] = __builtin_amdgcn_mfma_f32_16x16x32_bf16(ah[mt], vb[nt],  accv[mt][nt], 0, 0, 0);
                }
        }

        // issue next tile's loads NOW: they fly during the whole epilogue
        if (it + 1 < NT) {
            const float4* xg = (const float4*)(xbase + (size_t)(it + 1) * 64 * Fc);
#pragma unroll
            for (int i = 0; i < 4; i++) xr[i] = xg[i * 512 + t];
        }

        // exp -> eT bf16 [r][n-loc]; Z partials; per-n rowsum partials
        float sloc[2][4];
#pragma unroll
        for (int mt = 0; mt < 2; mt++)
#pragma unroll
            for (int reg = 0; reg < 4; reg++) {
                const int nl = 16 * mt + 4 * quad + reg;   // local n 0..31
                const float e0 = __expf((acca[mt][0][reg] + bqkv[0]) * SCALE);
                const float e1 = __expf((acca[mt][1][reg] + bqkv[1]) * SCALE);
                eT[l15 * 40 + nl]        = f2bf(e0);   // r = l15
                eT[(16 + l15) * 40 + nl] = f2bf(e1);   // r = 16 + l15
                zacc[0] += e0; zacc[1] += e1;
                sloc[mt][reg] = e0 + e1;
            }
        // butterfly over the 16-lane group: sloc becomes sum_r e[n][r]
#pragma unroll
        for (int m = 1; m < 16; m <<= 1)
#pragma unroll
            for (int mt = 0; mt < 2; mt++)
#pragma unroll
                for (int reg = 0; reg < 4; reg++)
                    sloc[mt][reg] += __shfl_xor(sloc[mt][reg], m);

        // xv -> xvT [d][n-loc] bf16, pre-scaled by 1/rowsum
#pragma unroll
        for (int mt = 0; mt < 2; mt++)
#pragma unroll
            for (int reg = 0; reg < 4; reg++) {
                const int nl = 16 * mt + 4 * quad + reg;
                const float sw = 1.f / sloc[mt][reg];
#pragma unroll
                for (int nt = 0; nt < 2; nt++)
                    xvT[(16 * nt + l15) * 40 + nl] =
                        f2bf((accv[mt][nt][reg] + bvv[nt]) * sw);
            }

        // v1[r][d] += sum_{n in wave's half} eT[r][n] * xvT[d][n]  (K=32)
        {
            short8 ae[2], bx[2];
#pragma unroll
            for (int i = 0; i < 2; i++) {
                ae[i] = *(const short8*)&eT[(16 * i + l15) * 40 + quad * 8];
                bx[i] = *(const short8*)&xvT[(16 * i + l15) * 40 + quad * 8];
            }
#pragma unroll
            for (int mt = 0; mt < 2; mt++)
#pragma unroll
                for (int nt = 0; nt < 2; nt++)
                    accV1[mt][nt] = __builtin_amdgcn_mfma_f32_16x16x32_bf16(ae[mt], bx[nt], accV1[mt][nt], 0, 0, 0);
        }
    }

    // Z: reduce over quads, atomic once per col (both halves add partials)
#pragma unroll
    for (int rt = 0; rt < 2; rt++) {
        float zr = zacc[rt];
        zr += __shfl_xor(zr, 16);
        zr += __shfl_xor(zr, 32);
        if (quad == 0)
            atomicAdd(&Z[((size_t)bt * Hh + h) * Rr + 16 * rt + l15], zr);
    }
    float* v1b = v1 + ((size_t)bt * Hh + h) * Rr * Dd;
#pragma unroll
    for (int mt = 0; mt < 2; mt++)
#pragma unroll
        for (int nt = 0; nt < 2; nt++)
#pragma unroll
            for (int reg = 0; reg < 4; reg++)
                atomicAdd(&v1b[(16 * mt + 4 * quad + reg) * 32 + 16 * nt + l15],
                          accV1[mt][nt][reg]);
}

// ---------------------------------------------------------------------------
// kb (pass B), 512 threads = 8 waves (same split). Recompute attn + xv
// (hi/lo), v2 = expa @ (v1/Z) via MFMA (vbz built per block from v1/Z).
// Per-wave acc halves; eS/fS per-wave scratch 4608 B; LDS 71680 ->
// 2 blocks/CU = 4 waves/SIMD. Output via fS -> dense float4 stores.
// ---------------------------------------------------------------------------
__global__ __launch_bounds__(512, 4)
void kb(const float* __restrict__ x, const float* __restrict__ bv,
        const ushort* __restrict__ U, const float* __restrict__ bqk,
        const float* __restrict__ v1, const float* __restrict__ Z,
        const float* __restrict__ alpha, const float* __restrict__ beta,
        float* __restrict__ out)
{
    // xhi [64][136] 17408 | xlo 17408 | 8x per-wave scratch 4608
    __shared__ __align__(16) char lds[71680];
    ushort* xhi = (ushort*)lds;
    ushort* xlo = (ushort*)(lds + 17408);

    const int t = threadIdx.x;
    const int w = t >> 6, lane = t & 63;
    const int h = w & 3, half = w >> 2;
    const int quad = lane >> 4, l15 = lane & 15;
    const int bt = blockIdx.y;
    constexpr int NT = 4;

    char* wsc = lds + 34816 + w * 4608;
    ushort* eS = (ushort*)wsc;   // [32][40] bf16 (2560 B)
    float*  fS = (float*)wsc;    // [32][36] f32 (4608 B) overlay, 144 B rows

    const ushort* WKh = U + U_WKHI;
    const ushort* Wvh = U + U_WVHI;
    const ushort* Wvl = U + U_WVLO;

    float bqkv[2], bvv[2];
#pragma unroll
    for (int i = 0; i < 2; i++) {
        bqkv[i] = bqk[32 * h + 16 * i + l15];
        bvv[i]  = bv[32 * h + 16 * i + l15];
    }

    // build vbz B-frag: vbz[dt] lane(q,l15) = bf16(v1[r=8q+j][d=16dt+l15]/Z[r])
    const float* v1h = v1 + ((size_t)bt * Hh + h) * Rr * Dd;
    const float* Zh  = Z + ((size_t)bt * Hh + h) * Rr;
    float zr8[8];
#pragma unroll
    for (int j = 0; j < 8; j++) zr8[j] = 1.f / Zh[8 * quad + j];
    short8 vbz[2];
#pragma unroll
    for (int dt = 0; dt < 2; dt++) {
        union { short8 s; unsigned u[4]; } uu;
#pragma unroll
        for (int jj = 0; jj < 4; jj++) {
            const float a0 = v1h[(8 * quad + 2 * jj) * 32 + 16 * dt + l15] * zr8[2 * jj];
            const float a1 = v1h[(8 * quad + 2 * jj + 1) * 32 + 16 * dt + l15] * zr8[2 * jj + 1];
            uu.u[jj] = ((unsigned)f2bf(a1) << 16) | f2bf(a0);
        }
        vbz[dt] = uu.s;
    }
    const float sa = 1.f / (1.f + __expf(-alpha[h]));
    const float sb = 1.f / (1.f + __expf(-beta[h]));

    const float* xbase = x + ((size_t)bt * Nn + blockIdx.x * (NT * 64)) * Fc;
    float* obase = out + ((size_t)bt * Nn + blockIdx.x * (NT * 64)) * Fc;

    float4 xr[4];
#pragma unroll
    for (int i = 0; i < 4; i++) xr[i] = ((const float4*)xbase)[i * 512 + t];

#pragma unroll 1
    for (int it = 0; it < NT; ++it) {
        // regs -> LDS hi/lo (waits on prefetch)
#pragma unroll
        for (int i = 0; i < 4; i++) {
            const int idx = i * 512 + t;
            const int row = idx >> 5, c4 = idx & 31;
            float4 v = xr[i];
            ushort h0 = f2bf(v.x), h1 = f2bf(v.y), h2 = f2bf(v.z), h3 = f2bf(v.w);
            ushort4 hv; hv.x = h0; hv.y = h1; hv.z = h2; hv.w = h3;
            ushort4 lv; lv.x = f2bf(v.x - bf2f(h0)); lv.y = f2bf(v.y - bf2f(h1));
            lv.z = f2bf(v.z - bf2f(h2)); lv.w = f2bf(v.w - bf2f(h3));
            *(ushort4*)&xhi[row * 136 + c4 * 4] = hv;
            *(ushort4*)&xlo[row * 136 + c4 * 4] = lv;
        }
        __syncthreads();   // b1

        floatx4 acca[2][2], accv[2][2];
#pragma unroll
        for (int mt = 0; mt < 2; mt++)
#pragma unroll
            for (int nt = 0; nt < 2; nt++) {
                acca[mt][nt] = (floatx4)0.f;
                accv[mt][nt] = (floatx4)0.f;
            }

#pragma unroll
        for (int kc = 0; kc < 4; kc++) {
            short8 ahi[2], alo[2];
#pragma unroll
            for (int mt = 0; mt < 2; mt++) {
                const int ro = (32 * half + 16 * mt + l15) * 136 + kc * 32 + quad * 8;
                ahi[mt] = *(const short8*)&xhi[ro];
                alo[mt] = *(const short8*)&xlo[ro];
            }
            short8 kb2[2], vbh[2], vbl[2];
#pragma unroll
            for (int nt = 0; nt < 2; nt++) {
                const int off = (32 * h + 16 * nt + l15) * 128 + kc * 32 + quad * 8;
                kb2[nt] = *(const short8*)&WKh[off];
                vbh[nt] = *(const short8*)&Wvh[off];
                vbl[nt] = *(const short8*)&Wvl[off];
            }
#pragma unroll
            for (int mt = 0; mt < 2; mt++)
#pragma unroll
                for (int nt = 0; nt < 2; nt++) {
                    acca[mt][nt] = __builtin_amdgcn_mfma_f32_16x16x32_bf16(ahi[mt], kb2[nt], acca[mt][nt], 0, 0, 0);
                    accv[mt][nt] = __builtin_amdgcn_mfma_f32_16x16x32_bf16(ahi[mt], vbh[nt], accv[mt][nt], 0, 0, 0);
                    accv[mt][nt] = __builtin_amdgcn_mfma_f32_16x16x32_bf16(ahi[mt], vbl[nt], accv[mt][nt], 0, 0, 0);
                    accv[mt][nt] = __builtin_amdgcn_mfma_f32_16x16x32_bf16(alo[mt], vbh[nt], accv[mt][nt], 0, 0, 0);
                }
        }
        __syncthreads();   // b2: xhi/xlo reads done

        // issue next tile's loads: in flight through the whole epilogue
        if (it + 1 < NT) {
            const float4* xg = (const float4*)(xbase + (size_t)(it + 1) * 64 * Fc);
#pragma unroll
            for (int i = 0; i < 4; i++) xr[i] = xg[i * 512 + t];
        }

        // exp -> eS; v2 = expa @ vbz; mix -> fS; dense float4 stores
#pragma unroll
        for (int mt = 0; mt < 2; mt++)
#pragma unroll
            for (int rt = 0; rt < 2; rt++)
#pragma unroll
                for (int reg = 0; reg < 4; reg++) {
                    const int row = 16 * mt + 4 * quad + reg;
                    eS[row * 40 + 16 * rt + l15] =
                        f2bf(__expf((acca[mt][rt][reg] + bqkv[rt]) * SCALE));
                }
        floatx4 acc2[2][2];
#pragma unroll
        for (int mt = 0; mt < 2; mt++) {
            short8 pa = *(const short8*)&eS[(16 * mt + l15) * 40 + quad * 8];
#pragma unroll
            for (int dt = 0; dt < 2; dt++) {
                acc2[mt][dt] = (floatx4)0.f;
                acc2[mt][dt] = __builtin_amdgcn_mfma_f32_16x16x32_bf16(pa, vbz[dt], acc2[mt][dt], 0, 0, 0);
            }
        }
#pragma unroll
        for (int mt = 0; mt < 2; mt++)
#pragma unroll
            for (int nt = 0; nt < 2; nt++)
#pragma unroll
                for (int reg = 0; reg < 4; reg++) {
                    const int row = 16 * mt + 4 * quad + reg;
                    fS[row * 36 + 16 * nt + l15] =
                        sa * (accv[mt][nt][reg] + bvv[nt]) + sb * acc2[mt][nt][reg];
                }
        float* op = obase + (size_t)it * 64 * Fc;
#pragma unroll
        for (int i = 0; i < 4; i++) {
            const int idx = i * 64 + lane;
            const int n = idx >> 3, c4 = idx & 7;   // n 0..31 local
            *(float4*)&op[(size_t)(32 * half + n) * 128 + h * 32 + c4 * 4] =
                *(const float4*)&fS[n * 36 + c4 * 4];
        }
    }
}

// ---------------------------------------------------------------------------
extern "C" void kernel_launch(void* const* d_in, const int* in_sizes, int n_in,
                              void* d_out, int out_size, void* d_ws, size_t ws_size,
                              hipStream_t stream)
{
    const float* x     = (const float*)d_in[0];
    const float* Wq    = (const float*)d_in[1];
    const float* bq    = (const float*)d_in[2];
    const float* key   = (const float*)d_in[3];
    const float* Wv    = (const float*)d_in[4];
    const float* bv    = (const float*)d_in[5];
    const float* alpha = (const float*)d_in[6];
    const float* beta  = (const float*)d_in[7];
    float* out = (float*)d_out;

    float*  ws   = (float*)d_ws;
    float*  v1   = ws + OFF_V1;
    float*  Zb   = ws + OFF_Z;
    float*  bqkp = ws + OFF_BQK;
    ushort* U    = (ushort*)(ws + OFF_U);

    hipMemsetAsync(v1, 0,
                   (size_t)(BT * Hh * Rr * Dd + BT * Hh * Rr) * sizeof(float),
                   stream);
    kprep<<<dim3(129), 256, 0, stream>>>(Wq, bq, Wv, key, U, bqkp);
    ka<<<dim3(16, BT), 512, 0, stream>>>(x, bv, U, bqkp, v1, Zb);
    kb<<<dim3(16, BT), 512, 0, stream>>>(x, bv, U, bqkp, v1, Zb, alpha, beta, out);
}